// Round 1
// baseline (1246.978 us; speedup 1.0000x reference)
//
#include <hip/hip_runtime.h>

#define NB 64
#define NFB 257
#define NANG 360

// ---------------------------------------------------------------------------
// Fused conv3x3(SAME) + BN + ReLU + maxpool2.  PT=16 pre-pool tile, 256 thr.
// Thread tile: 2 out-channels x 4x4 pre-pool positions (=> 2x2 pooled).
// ---------------------------------------------------------------------------
template<int IC, int CC, int HIN, int WIN, int OT>
__global__ __launch_bounds__(256)
void conv_block_kernel(const float* __restrict__ in, const float* __restrict__ w,
                       const float* __restrict__ gg, const float* __restrict__ bb,
                       const float* __restrict__ bm, const float* __restrict__ bv,
                       float* __restrict__ out, int OC)
{
    constexpr int PT = 16;
    constexpr int HOUT = HIN / 2, WOUT = WIN / 2;
    constexpr int SW = WIN / PT;
    constexpr int STILES = (HIN / PT) * SW;
    constexpr int WSTR = CC * 9 + 1;         // +1 pad: avoids 4-way LDS bank conflict

    __shared__ float Xs[CC][18 * 20];        // 18x18 halo tile, row stride 20
    __shared__ float Ws[OT][WSTR];

    int bid = blockIdx.x;
    int stile = bid % STILES; bid /= STILES;
    int OTILES = (OC + OT - 1) / OT;
    int otile = bid % OTILES;
    int b = bid / OTILES;

    int ty = (stile / SW) * PT, tx = (stile % SW) * PT;
    int o0 = otile * OT;

    int tid = threadIdx.x;
    int ogrp = tid >> 4;                     // 0..15 -> 2 oc each
    int sgrp = tid & 15;                     // 0..15 -> 4x4 spatial patch
    int sy = sgrp >> 2, sx = sgrp & 3;
    int py0 = sy * 4, px0 = sx * 4;

    float acc[2][4][4];
    #pragma unroll
    for (int i = 0; i < 2; ++i)
        #pragma unroll
        for (int y = 0; y < 4; ++y)
            #pragma unroll
            for (int x = 0; x < 4; ++x) acc[i][y][x] = 0.f;

    for (int ic0 = 0; ic0 < IC; ic0 += CC) {
        __syncthreads();
        // stage input chunk (with SAME-pad halo)
        for (int i = tid; i < CC * 324; i += 256) {
            int cc = i / 324; int rem = i % 324;
            int r = rem / 18, cl = rem % 18;
            int gy = ty - 1 + r, gxx = tx - 1 + cl;
            float v = 0.f;
            if (gy >= 0 && gy < HIN && gxx >= 0 && gxx < WIN)
                v = in[(((size_t)b * IC + ic0 + cc) * HIN + gy) * WIN + gxx];
            Xs[cc][r * 20 + cl] = v;
        }
        // stage weight chunk
        for (int i = tid; i < OT * CC * 9; i += 256) {
            int ol = i / (CC * 9); int rem = i % (CC * 9);
            int o = o0 + ol;
            float v = 0.f;
            if (o < OC) {
                int cc = rem / 9, k = rem % 9;
                v = w[((size_t)o * IC + ic0 + cc) * 9 + k];
            }
            Ws[ol][rem] = v;
        }
        __syncthreads();

        for (int cc = 0; cc < CC; ++cc) {
            float p[6][6];
            #pragma unroll
            for (int dy = 0; dy < 6; ++dy)
                #pragma unroll
                for (int dx = 0; dx < 6; ++dx)
                    p[dy][dx] = Xs[cc][(py0 + dy) * 20 + (px0 + dx)];
            float w0[9], w1[9];
            #pragma unroll
            for (int k = 0; k < 9; ++k) {
                w0[k] = Ws[ogrp * 2][cc * 9 + k];
                w1[k] = Ws[ogrp * 2 + 1][cc * 9 + k];
            }
            #pragma unroll
            for (int ky = 0; ky < 3; ++ky)
                #pragma unroll
                for (int kx = 0; kx < 3; ++kx) {
                    float wa = w0[ky * 3 + kx], wbv = w1[ky * 3 + kx];
                    #pragma unroll
                    for (int y = 0; y < 4; ++y)
                        #pragma unroll
                        for (int x = 0; x < 4; ++x) {
                            float pv = p[y + ky][x + kx];
                            acc[0][y][x] = fmaf(pv, wa, acc[0][y][x]);
                            acc[1][y][x] = fmaf(pv, wbv, acc[1][y][x]);
                        }
                }
        }
    }
    // epilogue: BN + ReLU + 2x2 max-pool (relu(max) == max(relu))
    #pragma unroll
    for (int i = 0; i < 2; ++i) {
        int o = o0 + ogrp * 2 + i;
        if (o >= OC) continue;
        float scale = gg[o] * rsqrtf(bv[o] + 1e-5f);
        float bias  = bb[o] - bm[o] * scale;
        #pragma unroll
        for (int y2 = 0; y2 < 2; ++y2)
            #pragma unroll
            for (int x2 = 0; x2 < 2; ++x2) {
                float m = -3.4e38f;
                #pragma unroll
                for (int dy = 0; dy < 2; ++dy)
                    #pragma unroll
                    for (int dx = 0; dx < 2; ++dx)
                        m = fmaxf(m, fmaf(acc[i][y2 * 2 + dy][x2 * 2 + dx], scale, bias));
                m = fmaxf(m, 0.f);
                int py = ty / 2 + sy * 2 + y2;
                int px = tx / 2 + sx * 2 + x2;
                out[(((size_t)b * OC + o) * HOUT + py) * WOUT + px] = m;
            }
    }
}

// ---------------------------------------------------------------------------
// FC: (B*257, 64) @ (32,64)^T + b  ->  (B*257, 32)
// ---------------------------------------------------------------------------
__global__ __launch_bounds__(256)
void fc_kernel(const float* __restrict__ zin, const float* __restrict__ fw,
               const float* __restrict__ fb, float* __restrict__ zout)
{
    __shared__ float wsT[64 * 33];           // transposed, stride 33: conflict-free
    int tid = threadIdx.x;
    for (int i = tid; i < 32 * 64; i += 256) {
        int j = i / 64, s = i % 64;
        wsT[s * 33 + j] = fw[i];
    }
    __syncthreads();
    int idx = blockIdx.x * 256 + tid;
    int j = idx & 31, r = idx >> 5;
    const float* zr = zin + (size_t)r * 64;
    float acc = fb[j];
    #pragma unroll 8
    for (int s = 0; s < 64; ++s)
        acc = fmaf(zr[s], wsT[s * 33 + j], acc);
    zout[idx] = acc;
}

// ---------------------------------------------------------------------------
// Per-thread 4x4 Hermitian eigh (cyclic complex Jacobi, double precision).
// Emits Re(Un Un^H) (projector onto 2 smallest-eigenvalue eigenvectors).
// ---------------------------------------------------------------------------
__global__ __launch_bounds__(64)
void eigh_kernel(const float* __restrict__ z, double* __restrict__ rp)
{
    int idx = blockIdx.x * 64 + threadIdx.x;
    if (idx >= NB * NFB) return;
    const float* zr = z + (size_t)idx * 32;  // (4,8): [m][n]=re, [m][n+4]=im
    double Ar[4][4], Ai[4][4], Vr[4][4], Vi[4][4];
    #pragma unroll
    for (int m = 0; m < 4; ++m)
        #pragma unroll
        for (int n = 0; n < 4; ++n) {
            Ar[m][n] = 0.5 * ((double)zr[m * 8 + n] + (double)zr[n * 8 + m]);
            Ai[m][n] = 0.5 * ((double)zr[m * 8 + n + 4] - (double)zr[n * 8 + m + 4]);
            Vr[m][n] = (m == n) ? 1.0 : 0.0;
            Vi[m][n] = 0.0;
        }
    #pragma unroll
    for (int m = 0; m < 4; ++m) Ar[m][m] += 1e-5;

    for (int sweep = 0; sweep < 8; ++sweep) {
        #pragma unroll
        for (int p = 0; p < 3; ++p)
            #pragma unroll
            for (int q = p + 1; q < 4; ++q) {
                double apr = Ar[p][q], api = Ai[p][q];
                double rmod = sqrt(apr * apr + api * api);
                if (rmod < 1e-300) continue;
                double cph = apr / rmod, sph = api / rmod;     // e^{i phi}
                double tau = (Ar[q][q] - Ar[p][p]) / (2.0 * rmod);
                double t = (tau >= 0.0) ? (-1.0 / (tau + sqrt(1.0 + tau * tau)))
                                        : ( 1.0 / (-tau + sqrt(1.0 + tau * tau)));
                double c = 1.0 / sqrt(1.0 + t * t);
                double s = t * c;
                double wr = s * cph, wi = s * sph;             // w = s e^{i phi}
                #pragma unroll
                for (int i = 0; i < 4; ++i) {                  // A <- A U
                    double xr = Ar[i][p], xi = Ai[i][p];
                    double yr = Ar[i][q], yi = Ai[i][q];
                    Ar[i][p] = c * xr + (wr * yr + wi * yi);
                    Ai[i][p] = c * xi + (wr * yi - wi * yr);
                    Ar[i][q] = c * yr - (wr * xr - wi * xi);
                    Ai[i][q] = c * yi - (wr * xi + wi * xr);
                }
                #pragma unroll
                for (int i = 0; i < 4; ++i) {                  // A <- U^H A
                    double xr = Ar[p][i], xi = Ai[p][i];
                    double yr = Ar[q][i], yi = Ai[q][i];
                    Ar[p][i] = c * xr + (wr * yr - wi * yi);
                    Ai[p][i] = c * xi + (wr * yi + wi * yr);
                    Ar[q][i] = c * yr - (wr * xr + wi * xi);
                    Ai[q][i] = c * yi - (wr * xi - wi * xr);
                }
                #pragma unroll
                for (int i = 0; i < 4; ++i) {                  // V <- V U
                    double xr = Vr[i][p], xi = Vi[i][p];
                    double yr = Vr[i][q], yi = Vi[i][q];
                    Vr[i][p] = c * xr + (wr * yr + wi * yi);
                    Vi[i][p] = c * xi + (wr * yi - wi * yr);
                    Vr[i][q] = c * yr - (wr * xr - wi * xi);
                    Vi[i][q] = c * yi - (wr * xi + wi * xr);
                }
            }
    }
    double ev[4] = {Ar[0][0], Ar[1][1], Ar[2][2], Ar[3][3]};
    int i0 = 0;
    #pragma unroll
    for (int k = 1; k < 4; ++k) if (ev[k] < ev[i0]) i0 = k;
    int i1 = (i0 == 0) ? 1 : 0;
    #pragma unroll
    for (int k = 0; k < 4; ++k) if (k != i0 && ev[k] < ev[i1]) i1 = k;
    double* o = rp + (size_t)idx * 16;
    #pragma unroll
    for (int m = 0; m < 4; ++m)
        #pragma unroll
        for (int n = 0; n < 4; ++n)
            o[m * 4 + n] = Vr[m][i0] * Vr[n][i0] + Vi[m][i0] * Vi[n][i0]
                         + Vr[m][i1] * Vr[n][i1] + Vi[m][i1] * Vi[n][i1];
}

// ---------------------------------------------------------------------------
// MUSIC pseudo-spectrum.  denom = u^T P u - w^T P w (P = Re(UnUn^H)),
// which equals Re(einsum(svc,UnUnH,svc)) analytically.
// ---------------------------------------------------------------------------
__global__ __launch_bounds__(384)
void music_kernel(const float4* __restrict__ svr, const float4* __restrict__ svi,
                  const double* __restrict__ rp, float* __restrict__ sp)
{
    int bf = blockIdx.x;
    __shared__ double P[16];
    if (threadIdx.x < 16) P[threadIdx.x] = rp[(size_t)bf * 16 + threadIdx.x];
    __syncthreads();
    int a = threadIdx.x;
    if (a >= NANG) return;
    float4 u4 = svr[(size_t)bf * NANG + a];
    float4 w4 = svi[(size_t)bf * NANG + a];
    double ua[4] = {u4.x, u4.y, u4.z, u4.w};
    double wa[4] = {w4.x, w4.y, w4.z, w4.w};
    double qa = 0.0, qb = 0.0;
    #pragma unroll
    for (int m = 0; m < 4; ++m)
        #pragma unroll
        for (int n = 0; n < 4; ++n) {
            double pmn = P[m * 4 + n];
            qa += pmn * ua[m] * ua[n];
            qb += pmn * wa[m] * wa[n];
        }
    double den = qa - qb;
    sp[(size_t)bf * NANG + a] = (float)(1.0 / fmax(den, 1e-6));
}

// ---------------------------------------------------------------------------
// conv1d 257->257 (k=3, SAME) + bias + leaky_relu(0.1).  Tiled 64o x 64t,
// thread tile 4x4.
// ---------------------------------------------------------------------------
__global__ __launch_bounds__(256)
void convs2_kernel(const float* __restrict__ sp1, const float* __restrict__ w,
                   const float* __restrict__ bia, float* __restrict__ sp2)
{
    __shared__ float Xs[8][66];
    __shared__ float Ws2[8][192];
    int bid = blockIdx.x;
    int tt = bid % 6; bid /= 6;
    int ot = bid % 5; int b = bid / 5;
    int t0 = tt * 64, o0 = ot * 64;
    int tid = threadIdx.x;
    int tr = tid >> 4, tc = tid & 15;

    float acc[4][4];
    #pragma unroll
    for (int i = 0; i < 4; ++i)
        #pragma unroll
        for (int j = 0; j < 4; ++j) acc[i][j] = 0.f;

    const float* spb = sp1 + (size_t)b * NFB * NANG;

    for (int c0 = 0; c0 < NFB; c0 += 8) {
        __syncthreads();
        for (int i = tid; i < 8 * 66; i += 256) {
            int cc = i / 66, s = i % 66;
            int c = c0 + cc, t = t0 - 1 + s;
            float v = 0.f;
            if (c < NFB && t >= 0 && t < NANG) v = spb[(size_t)c * NANG + t];
            Xs[cc][s] = v;
        }
        for (int i = tid; i < 8 * 192; i += 256) {
            int cc = i / 192, r = i % 192;
            int c = c0 + cc, o = o0 + r / 3;
            float v = 0.f;
            if (c < NFB && o < NFB) v = w[((size_t)o * NFB + c) * 3 + (r % 3)];
            Ws2[cc][r] = v;
        }
        __syncthreads();
        #pragma unroll
        for (int cc = 0; cc < 8; ++cc) {
            float x[6];
            #pragma unroll
            for (int j = 0; j < 6; ++j) x[j] = Xs[cc][tc * 4 + j];
            #pragma unroll
            for (int oj = 0; oj < 4; ++oj) {
                float wv0 = Ws2[cc][(tr * 4 + oj) * 3 + 0];
                float wv1 = Ws2[cc][(tr * 4 + oj) * 3 + 1];
                float wv2 = Ws2[cc][(tr * 4 + oj) * 3 + 2];
                #pragma unroll
                for (int tj = 0; tj < 4; ++tj) {
                    acc[oj][tj] = fmaf(wv0, x[tj], acc[oj][tj]);
                    acc[oj][tj] = fmaf(wv1, x[tj + 1], acc[oj][tj]);
                    acc[oj][tj] = fmaf(wv2, x[tj + 2], acc[oj][tj]);
                }
            }
        }
    }
    #pragma unroll
    for (int oj = 0; oj < 4; ++oj) {
        int o = o0 + tr * 4 + oj;
        if (o >= NFB) continue;
        float bo = bia[o];
        #pragma unroll
        for (int tj = 0; tj < 4; ++tj) {
            int t = t0 + tc * 4 + tj;
            if (t >= NANG) continue;
            float v = acc[oj][tj] + bo;
            v = (v >= 0.f) ? v : 0.1f * v;
            sp2[((size_t)b * NFB + o) * NANG + t] = v;
        }
    }
}

// ---------------------------------------------------------------------------
// Channel attention: y = mean_t sp2 ; att = sigmoid(relu(y W1^T) W2^T)
// ---------------------------------------------------------------------------
__global__ __launch_bounds__(320)
void attn_kernel(const float* __restrict__ sp2, const float* __restrict__ w1,
                 const float* __restrict__ w2, float* __restrict__ att)
{
    __shared__ float ys[NFB];
    __shared__ float hs[16];
    int b = blockIdx.x;
    int tid = threadIdx.x;
    int wid = tid >> 6, lane = tid & 63;
    for (int c = wid; c < NFB; c += 5) {
        const float* row = sp2 + ((size_t)b * NFB + c) * NANG;
        float s = 0.f;
        for (int t = lane; t < NANG; t += 64) s += row[t];
        #pragma unroll
        for (int off = 32; off > 0; off >>= 1)
            s += __shfl_down(s, off, 64);
        if (lane == 0) ys[c] = s * (1.0f / 360.0f);
    }
    __syncthreads();
    if (tid < 16) {
        float h = 0.f;
        for (int c = 0; c < NFB; ++c) h = fmaf(ys[c], w1[(size_t)tid * NFB + c], h);
        hs[tid] = fmaxf(h, 0.f);
    }
    __syncthreads();
    for (int o = tid; o < NFB; o += 320) {
        float a = 0.f;
        #pragma unroll
        for (int j = 0; j < 16; ++j) a = fmaf(hs[j], w2[(size_t)o * 16 + j], a);
        att[(size_t)b * NFB + o] = 1.0f / (1.0f + expf(-a));
    }
}

// ---------------------------------------------------------------------------
// conv1d 257->1 (k=3, SAME) over (sp2 * att) + bias, sigmoid -> (B,360)
// ---------------------------------------------------------------------------
__global__ __launch_bounds__(384)
void convs1_kernel(const float* __restrict__ sp2, const float* __restrict__ att,
                   const float* __restrict__ w, const float* __restrict__ bb,
                   float* __restrict__ outSpec)
{
    int b = blockIdx.x;
    __shared__ float wa[NFB * 3];
    for (int i = threadIdx.x; i < NFB * 3; i += 384) {
        int c = i / 3;
        wa[i] = w[i] * att[(size_t)b * NFB + c];
    }
    __syncthreads();
    int t = threadIdx.x;
    if (t >= NANG) return;
    const float* spb = sp2 + (size_t)b * NFB * NANG;
    float acc = bb[0];
    for (int c = 0; c < NFB; ++c) {
        const float* row = spb + (size_t)c * NANG;
        float x0 = (t > 0)        ? row[t - 1] : 0.f;
        float x1 = row[t];
        float x2 = (t < NANG - 1) ? row[t + 1] : 0.f;
        acc = fmaf(wa[c * 3 + 0], x0, acc);
        acc = fmaf(wa[c * 3 + 1], x1, acc);
        acc = fmaf(wa[c * 3 + 2], x2, acc);
    }
    outSpec[(size_t)b * NANG + t] = 1.0f / (1.0f + expf(-acc));
}

// ---------------------------------------------------------------------------
// top-5 soft-argmax (strict >: lowest index wins ties, matching lax.top_k)
// ---------------------------------------------------------------------------
__global__ __launch_bounds__(64)
void doa_kernel(const float* __restrict__ spec, float* __restrict__ doa)
{
    int b = threadIdx.x;
    const float* s = spec + (size_t)b * NANG;
    int idxs[5]; float vals[5];
    #pragma unroll
    for (int k = 0; k < 5; ++k) {
        float best = -3.4e38f; int bi = 0;
        for (int i = 0; i < NANG; ++i) {
            bool skip = false;
            #pragma unroll
            for (int j = 0; j < 5; ++j)
                if (j < k && idxs[j] == i) skip = true;
            float v = s[i];
            if (!skip && v > best) { best = v; bi = i; }
        }
        idxs[k] = bi; vals[k] = best;
    }
    float m = vals[0];
    float wsum = 0.f, asum = 0.f;
    #pragma unroll
    for (int k = 0; k < 5; ++k) {
        float wv = expf(20.0f * (vals[k] - m));
        wsum += wv;
        asum += wv * (float)idxs[k];   // angles[i] == i degrees
    }
    doa[b] = asum / wsum;
}

// ---------------------------------------------------------------------------
extern "C" void kernel_launch(void* const* d_in, const int* in_sizes, int n_in,
                              void* d_out, int out_size, void* d_ws, size_t ws_size,
                              hipStream_t stream)
{
    const float* X    = (const float*)d_in[0];
    const float* svr  = (const float*)d_in[1];
    const float* svi  = (const float*)d_in[2];
    const float* c1w  = (const float*)d_in[4];
    const float* c2w  = (const float*)d_in[5];
    const float* c3w  = (const float*)d_in[6];
    const float* c4w  = (const float*)d_in[7];
    const float* fcw  = (const float*)d_in[8];
    const float* fcb  = (const float*)d_in[9];
    const float* s2w  = (const float*)d_in[10];
    const float* s2b  = (const float*)d_in[11];
    const float* s1w  = (const float*)d_in[12];
    const float* s1b  = (const float*)d_in[13];
    const float* caw1 = (const float*)d_in[14];
    const float* caw2 = (const float*)d_in[15];
    const float* bn1g = (const float*)d_in[16]; const float* bn1b = (const float*)d_in[17];
    const float* bn1m = (const float*)d_in[18]; const float* bn1v = (const float*)d_in[19];
    const float* bn2g = (const float*)d_in[20]; const float* bn2b = (const float*)d_in[21];
    const float* bn2m = (const float*)d_in[22]; const float* bn2v = (const float*)d_in[23];
    const float* bn3g = (const float*)d_in[24]; const float* bn3b = (const float*)d_in[25];
    const float* bn3m = (const float*)d_in[26]; const float* bn3v = (const float*)d_in[27];
    const float* bn4g = (const float*)d_in[28]; const float* bn4b = (const float*)d_in[29];
    const float* bn4m = (const float*)d_in[30]; const float* bn4v = (const float*)d_in[31];

    float* ws = (float*)d_ws;
    // live-range reuse; peak = buf1+buf2 = 83.9 MB
    float*  buf1 = ws;                       // 16777216 f  (64,64,64,64)
    float*  buf2 = ws + 16777216;            //  4194304 f  (64,64,32,32)
    float*  buf3 = ws;                       //  1048576 f  (64,64,16,16)  (buf1 dead)
    float*  buf4 = ws + 1048576;             //  1052672 f  (64,257,8,8)
    float*  zfc  = ws + 2101248;             //   526336 f  (64,257,32)
    double* rpd  = (double*)(ws + 2627584);  //   263168 d  (= 526336 f)
    float*  sp1  = ws + 3153920;             //  5921280 f
    float*  sp2  = ws + 9075200;             //  5921280 f
    float*  attb = ws + 14996480;            //    16448 f
    float*  outD = (float*)d_out;            // doa (64)
    float*  outS = (float*)d_out + 64;       // spectrum (64*360)

    conv_block_kernel<8, 8, 128, 128, 32><<<NB * 2 * 64, 256, 0, stream>>>(
        X, c1w, bn1g, bn1b, bn1m, bn1v, buf1, 64);
    conv_block_kernel<64, 16, 64, 64, 32><<<NB * 2 * 16, 256, 0, stream>>>(
        buf1, c2w, bn2g, bn2b, bn2m, bn2v, buf2, 64);
    conv_block_kernel<64, 16, 32, 32, 32><<<NB * 2 * 4, 256, 0, stream>>>(
        buf2, c3w, bn3g, bn3b, bn3m, bn3v, buf3, 64);
    conv_block_kernel<64, 16, 16, 16, 32><<<NB * 9 * 1, 256, 0, stream>>>(
        buf3, c4w, bn4g, bn4b, bn4m, bn4v, buf4, 257);

    fc_kernel<<<(NB * NFB * 32) / 256, 256, 0, stream>>>(buf4, fcw, fcb, zfc);
    eigh_kernel<<<NFB, 64, 0, stream>>>(zfc, rpd);
    music_kernel<<<NB * NFB, 384, 0, stream>>>(
        (const float4*)svr, (const float4*)svi, rpd, sp1);
    convs2_kernel<<<NB * 5 * 6, 256, 0, stream>>>(sp1, s2w, s2b, sp2);
    attn_kernel<<<NB, 320, 0, stream>>>(sp2, caw1, caw2, attb);
    convs1_kernel<<<NB, 384, 0, stream>>>(sp2, attb, s1w, s1b, outS);
    doa_kernel<<<1, 64, 0, stream>>>(outS, outD);
}

// Round 2
// 600.582 us; speedup vs baseline: 2.0763x; 2.0763x over previous
//
#include <hip/hip_runtime.h>

typedef unsigned short u16;
typedef unsigned int u32;
typedef short short8 __attribute__((ext_vector_type(8)));
typedef float f32x4 __attribute__((ext_vector_type(4)));

#define NB 64
#define NFB 257
#define NANG 360

__device__ __forceinline__ u16 f2bf(float x) {
    u32 u = __float_as_uint(x);
    u = (u + 0x7fffu + ((u >> 16) & 1u)) >> 16;
    return (u16)u;
}
__device__ __forceinline__ float bf2f(u16 h) { return __uint_as_float(((u32)h) << 16); }

// ---------------------------------------------------------------------------
// BN fold: scale = g*rsqrt(v+eps), bias = b - m*scale.  4 layers, 1 launch.
// ---------------------------------------------------------------------------
__global__ __launch_bounds__(256) void bnprep(
    const float* g1, const float* b1, const float* m1, const float* v1,
    const float* g2, const float* b2, const float* m2, const float* v2,
    const float* g3, const float* b3, const float* m3, const float* v3,
    const float* g4, const float* b4, const float* m4, const float* v4,
    float* out)
{
    int L = blockIdx.x;
    const float* gs[4] = {g1, g2, g3, g4};
    const float* bs[4] = {b1, b2, b3, b4};
    const float* ms[4] = {m1, m2, m3, m4};
    const float* vs[4] = {v1, v2, v3, v4};
    int n = (L == 3) ? 257 : 64;
    float* sc = out + L * 1024;
    float* bi = sc + 512;
    for (int i = threadIdx.x; i < n; i += 256) {
        float s = gs[L][i] * rsqrtf(vs[L][i] + 1e-5f);
        sc[i] = s;
        bi[i] = bs[L][i] - ms[L][i] * s;
    }
}

// ---------------------------------------------------------------------------
// Weight pack: Bp[(chunk*2+h)*NFTOT + nf][lane][8] bf16, chunk = s*KCC + kc.
// lane l: k = kc*32 + (l>>4)*8 + e, n = nf*16 + (l&15).  h=0 hi, h=1 lo.
// w layout: w[(n*CREAL + k)*NT + s]  (covers OIHW 3x3 and OIH 3).
// ---------------------------------------------------------------------------
__global__ __launch_bounds__(256) void bpack(
    const float* __restrict__ w, u16* __restrict__ Bp,
    int CREAL, int OCREAL, int NT, int KCC, int NFTOT)
{
    int i = blockIdx.x * 256 + threadIdx.x;
    int total = NT * KCC * 2 * NFTOT * 64;
    if (i >= total) return;
    int lane = i & 63;
    int t = i >> 6;
    int nf = t % NFTOT;
    int th = t / NFTOT;
    int h = th & 1;
    int chunk = th >> 1;
    int s = chunk / KCC, kc = chunk % KCC;
    int n = nf * 16 + (lane & 15);
    int k0 = kc * 32 + (lane >> 4) * 8;
    u16 o8[8];
    #pragma unroll
    for (int e = 0; e < 8; ++e) {
        int k = k0 + e;
        float v = 0.f;
        if (k < CREAL && n < OCREAL) v = w[((size_t)n * CREAL + k) * NT + s];
        u16 hh = f2bf(v);
        o8[e] = (h == 0) ? hh : f2bf(v - bf2f(hh));
    }
    u16* d = Bp + (size_t)i * 8;
    #pragma unroll
    for (int e = 0; e < 8; ++e) d[e] = o8[e];
}

// ---------------------------------------------------------------------------
// X (64,8,128,128) f32 NCHW -> padded NHWC bf16 hi/lo (b,130,130,8)
// ---------------------------------------------------------------------------
__global__ __launch_bounds__(256) void xpack_kernel(
    const float* __restrict__ X, u16* __restrict__ hi, u16* __restrict__ lo)
{
    int bid = blockIdx.x;
    int prow = bid % 130;
    int b = bid / 130;
    for (int i = threadIdx.x; i < 8 * 130; i += 256) {
        int c = i / 130, pcol = i % 130;
        float v = 0.f;
        if (prow >= 1 && prow <= 128 && pcol >= 1 && pcol <= 128)
            v = X[(((size_t)b * 8 + c) * 128 + (prow - 1)) * 128 + (pcol - 1)];
        size_t o = (((size_t)b * 130 + prow) * 130 + pcol) * 8 + c;
        u16 hh = f2bf(v);
        hi[o] = hh;
        lo[o] = f2bf(v - bf2f(hh));
    }
}

// ---------------------------------------------------------------------------
// Zero the padding border of a padded-NHWC bf16 hi/lo pair.
// ---------------------------------------------------------------------------
__global__ __launch_bounds__(256) void zpad(
    u16* hi, u16* lo, int Bn, int Hp, int Wp, int Cb, int doCols)
{
    int perB = 2 * Wp + (doCols ? 2 * (Hp - 2) : 0);
    long total = (long)Bn * perB * Cb;
    for (long idx = blockIdx.x * 256L + threadIdx.x; idx < total; idx += (long)gridDim.x * 256) {
        int c = (int)(idx % Cb);
        long t = idx / Cb;
        int p = (int)(t % perB);
        int b = (int)(t / perB);
        int row, col;
        if (p < Wp) { row = 0; col = p; }
        else if (p < 2 * Wp) { row = Hp - 1; col = p - Wp; }
        else { int pp = p - 2 * Wp; row = 1 + (pp >> 1); col = (pp & 1) ? (Wp - 1) : 0; }
        size_t o = (((size_t)b * Hp + row) * Wp + col) * Cb + c;
        hi[o] = 0;
        lo[o] = 0;
    }
}

// ---------------------------------------------------------------------------
// Shift-GEMM conv via MFMA bf16 split (3 products: f32-quality).
// A: padded NHWC bf16 hi/lo.  B: bpack'd fragments.  256 thr = 4 waves.
// OUTMODE 0: BN+ReLU+pool2 -> padded NHWC bf16 hi/lo out
// OUTMODE 1: BN+ReLU+pool2 -> f32 NHWC out (b,H/2,W/2,OC)
// OUTMODE 2: +bias, leaky_relu(0.1) -> f32 out (b,H,OC)  (1D conv, W=1)
// ---------------------------------------------------------------------------
template<int C, int H, int W, int OC, int R, int KH, int KW, int NF, int MFW,
         int PSTR, int OUTMODE, bool CAPQ, int NFTOT>
__global__ __launch_bounds__(256) void conv_gemm(
    const u16* __restrict__ Ahi, const u16* __restrict__ Alo,
    const u16* __restrict__ Bp,
    const float* __restrict__ esc, const float* __restrict__ ebi,
    u16* __restrict__ Ohi, u16* __restrict__ Olo, float* __restrict__ Of)
{
    constexpr int KCC = (C + 31) / 32;
    constexpr int Wst = W + KW - 1;
    constexpr int Hp = H + KH - 1;
    constexpr int SROWS = R + KH - 1;
    constexpr int SPIX = SROWS * Wst;
    constexpr int CB16 = (C * 2 + 15) / 16;
    constexpr int CHUNKS = KH * KW * KCC;
    constexpr int OCB = NF * 16;
    constexpr int HT = (H + R - 1) / R;
    constexpr int STAGEB = SPIX * PSTR;
    constexpr int POOLB = (OUTMODE == 2) ? 0 : (R * W * OCB * 4);
    constexpr int SMEMB = (2 * STAGEB > POOLB) ? (2 * STAGEB) : POOLB;
    __shared__ __align__(16) char sm[SMEMB + 64];

    int bid = blockIdx.x;
    int ytile = bid % HT;
    int b = bid / HT;
    int tid = threadIdx.x;
    int wv = tid >> 6;
    int l = tid & 63;
    int r = l & 15, q = l >> 4;
    int y0 = ytile * R;

    // ---- stage padded input tile (hi then lo) ----
    for (int i = tid; i < SPIX * CB16; i += 256) {
        int pix = i / CB16, sub = i - pix * CB16;
        int prow = y0 + pix / Wst, pcol = pix % Wst;
        uint4 vh = {0, 0, 0, 0}, vl = {0, 0, 0, 0};
        if (prow < Hp) {
            size_t g = (((size_t)b * Hp + prow) * Wst + pcol) * (size_t)(C * 2) + (size_t)sub * 16;
            vh = *(const uint4*)((const char*)Ahi + g);
            vl = *(const uint4*)((const char*)Alo + g);
        }
        *(uint4*)(sm + pix * PSTR + sub * 16) = vh;
        *(uint4*)(sm + STAGEB + pix * PSTR + sub * 16) = vl;
    }
    __syncthreads();

    f32x4 acc[MFW][NF];
    #pragma unroll
    for (int mi = 0; mi < MFW; ++mi)
        #pragma unroll
        for (int ni = 0; ni < NF; ++ni)
            acc[mi][ni] = (f32x4){0.f, 0.f, 0.f, 0.f};

    for (int ch = 0; ch < CHUNKS; ++ch) {
        int s = ch / KCC, kc = ch % KCC;
        int ky = s / KW, kx = s % KW;
        short8 ah[MFW], al[MFW];
        #pragma unroll
        for (int mi = 0; mi < MFW; ++mi) {
            int mp0 = (wv * MFW + mi) * 16;
            int mpix = ((mp0 / W) + ky) * Wst + (mp0 % W) + kx;
            int off = (mpix + r) * PSTR + (CAPQ ? 0 : (q * 16 + kc * 64));
            ah[mi] = *(const short8*)(sm + off);
            al[mi] = *(const short8*)(sm + STAGEB + off);
        }
        #pragma unroll
        for (int ni = 0; ni < NF; ++ni) {
            int nfg = blockIdx.y * NF + ni;
            const u16* bt = Bp + ((size_t)(ch * 2) * NFTOT + nfg) * 512 + l * 8;
            short8 bh = *(const short8*)bt;
            short8 bl = *(const short8*)(bt + (size_t)NFTOT * 512);
            #pragma unroll
            for (int mi = 0; mi < MFW; ++mi) {
                acc[mi][ni] = __builtin_amdgcn_mfma_f32_16x16x32_bf16(ah[mi], bh, acc[mi][ni], 0, 0, 0);
                acc[mi][ni] = __builtin_amdgcn_mfma_f32_16x16x32_bf16(ah[mi], bl, acc[mi][ni], 0, 0, 0);
                acc[mi][ni] = __builtin_amdgcn_mfma_f32_16x16x32_bf16(al[mi], bh, acc[mi][ni], 0, 0, 0);
            }
        }
    }

    if (OUTMODE == 2) {
        // direct f32 write, +bias, leaky relu.  C/D: col=lane&15, row=(lane>>4)*4+j
        #pragma unroll
        for (int ni = 0; ni < NF; ++ni) {
            int nn = (blockIdx.y * NF + ni) * 16 + r;
            float bi0 = (nn < OC) ? ebi[nn] : 0.f;
            #pragma unroll
            for (int mi = 0; mi < MFW; ++mi) {
                #pragma unroll
                for (int j = 0; j < 4; ++j) {
                    int t = y0 + (wv * MFW + mi) * 16 + q * 4 + j;
                    if (t < H && nn < OC) {
                        float v = acc[mi][ni][j] + bi0;
                        Of[((size_t)b * H + t) * (size_t)OC + nn] = (v >= 0.f) ? v : 0.1f * v;
                    }
                }
            }
        }
    } else {
        __syncthreads();
        float* pt = (float*)sm;
        #pragma unroll
        for (int mi = 0; mi < MFW; ++mi)
            #pragma unroll
            for (int ni = 0; ni < NF; ++ni)
                #pragma unroll
                for (int j = 0; j < 4; ++j) {
                    int mp = (wv * MFW + mi) * 16 + q * 4 + j;
                    pt[mp * OCB + ni * 16 + r] = acc[mi][ni][j];
                }
        __syncthreads();
        constexpr int HO = H / 2, WO = W / 2;
        for (int i = tid; i < (R / 2) * WO * OCB; i += 256) {
            int c = i % OCB;
            int rem = i / OCB;
            int x2 = rem % WO;
            int y2 = rem / WO;
            int oc = blockIdx.y * OCB + c;
            float sc0 = 0.f, bi0 = 0.f;
            if (oc < OC) { sc0 = esc[oc]; bi0 = ebi[oc]; }
            float m = -3.4e38f;
            #pragma unroll
            for (int dy = 0; dy < 2; ++dy)
                #pragma unroll
                for (int dx = 0; dx < 2; ++dx) {
                    float v = fmaf(pt[((2 * y2 + dy) * W + 2 * x2 + dx) * OCB + c], sc0, bi0);
                    m = fmaxf(m, v);
                }
            m = fmaxf(m, 0.f);
            if (OUTMODE == 0) {
                size_t o = (((size_t)b * (HO + 2) + (y0 / 2 + y2 + 1)) * (WO + 2) + (x2 + 1)) * (size_t)OC + oc;
                u16 hh = f2bf(m);
                Ohi[o] = hh;
                Olo[o] = f2bf(m - bf2f(hh));
            } else {
                if (oc < OC)
                    Of[(((size_t)b * HO + (y0 / 2 + y2)) * WO + x2) * (size_t)OC + oc] = m;
            }
        }
    }
}

// ---------------------------------------------------------------------------
// FC: z (b, 64 pix, 257 f) NHWC f32 -> zfc (b, f, 32)
// ---------------------------------------------------------------------------
__global__ __launch_bounds__(256) void fc_kernel(
    const float* __restrict__ z, const float* __restrict__ fw,
    const float* __restrict__ fb, float* __restrict__ zfc)
{
    int bid = blockIdx.x;
    int ftile = bid % 33;
    int b = bid / 33;
    int j = threadIdx.x & 31;
    int f = ftile * 8 + (threadIdx.x >> 5);
    if (f >= 257) return;
    const float* zb = z + (size_t)b * 16448;
    float a = fb[j];
    #pragma unroll 8
    for (int s = 0; s < 64; ++s) a = fmaf(zb[s * 257 + f], fw[j * 64 + s], a);
    zfc[((size_t)b * 257 + f) * 32 + j] = a;
}

// ---------------------------------------------------------------------------
// Per-thread 4x4 Hermitian eigh (complex Jacobi, f64) -> Re(Un Un^H)
// ---------------------------------------------------------------------------
__global__ __launch_bounds__(64) void eigh_kernel(const float* __restrict__ z, double* __restrict__ rp)
{
    int idx = blockIdx.x * 64 + threadIdx.x;
    if (idx >= NB * NFB) return;
    const float* zr = z + (size_t)idx * 32;
    double Ar[4][4], Ai[4][4], Vr[4][4], Vi[4][4];
    #pragma unroll
    for (int m = 0; m < 4; ++m)
        #pragma unroll
        for (int n = 0; n < 4; ++n) {
            Ar[m][n] = 0.5 * ((double)zr[m * 8 + n] + (double)zr[n * 8 + m]);
            Ai[m][n] = 0.5 * ((double)zr[m * 8 + n + 4] - (double)zr[n * 8 + m + 4]);
            Vr[m][n] = (m == n) ? 1.0 : 0.0;
            Vi[m][n] = 0.0;
        }
    #pragma unroll
    for (int m = 0; m < 4; ++m) Ar[m][m] += 1e-5;

    for (int sweep = 0; sweep < 8; ++sweep) {
        #pragma unroll
        for (int p = 0; p < 3; ++p)
            #pragma unroll
            for (int qq = p + 1; qq < 4; ++qq) {
                double apr = Ar[p][qq], api = Ai[p][qq];
                double rmod = sqrt(apr * apr + api * api);
                if (rmod < 1e-300) continue;
                double cph = apr / rmod, sph = api / rmod;
                double tau = (Ar[qq][qq] - Ar[p][p]) / (2.0 * rmod);
                double t = (tau >= 0.0) ? (-1.0 / (tau + sqrt(1.0 + tau * tau)))
                                        : (1.0 / (-tau + sqrt(1.0 + tau * tau)));
                double c = 1.0 / sqrt(1.0 + t * t);
                double s = t * c;
                double wr = s * cph, wi = s * sph;
                #pragma unroll
                for (int i = 0; i < 4; ++i) {
                    double xr = Ar[i][p], xi = Ai[i][p];
                    double yr = Ar[i][qq], yi = Ai[i][qq];
                    Ar[i][p] = c * xr + (wr * yr + wi * yi);
                    Ai[i][p] = c * xi + (wr * yi - wi * yr);
                    Ar[i][qq] = c * yr - (wr * xr - wi * xi);
                    Ai[i][qq] = c * yi - (wr * xi + wi * xr);
                }
                #pragma unroll
                for (int i = 0; i < 4; ++i) {
                    double xr = Ar[p][i], xi = Ai[p][i];
                    double yr = Ar[qq][i], yi = Ai[qq][i];
                    Ar[p][i] = c * xr + (wr * yr - wi * yi);
                    Ai[p][i] = c * xi + (wr * yi + wi * yr);
                    Ar[qq][i] = c * yr - (wr * xr + wi * xi);
                    Ai[qq][i] = c * yi - (wr * xi - wi * xr);
                }
                #pragma unroll
                for (int i = 0; i < 4; ++i) {
                    double xr = Vr[i][p], xi = Vi[i][p];
                    double yr = Vr[i][qq], yi = Vi[i][qq];
                    Vr[i][p] = c * xr + (wr * yr + wi * yi);
                    Vi[i][p] = c * xi + (wr * yi - wi * yr);
                    Vr[i][qq] = c * yr - (wr * xr - wi * xi);
                    Vi[i][qq] = c * yi - (wr * xi + wi * xr);
                }
            }
    }
    double ev[4] = {Ar[0][0], Ar[1][1], Ar[2][2], Ar[3][3]};
    int i0 = 0;
    #pragma unroll
    for (int k = 1; k < 4; ++k) if (ev[k] < ev[i0]) i0 = k;
    int i1 = (i0 == 0) ? 1 : 0;
    #pragma unroll
    for (int k = 0; k < 4; ++k) if (k != i0 && ev[k] < ev[i1]) i1 = k;
    double* o = rp + (size_t)idx * 16;
    #pragma unroll
    for (int m = 0; m < 4; ++m)
        #pragma unroll
        for (int n = 0; n < 4; ++n)
            o[m * 4 + n] = Vr[m][i0] * Vr[n][i0] + Vi[m][i0] * Vi[n][i0]
                         + Vr[m][i1] * Vr[n][i1] + Vi[m][i1] * Vi[n][i1];
}

// ---------------------------------------------------------------------------
// MUSIC spectrum -> transposed padded split output (b, t=a+1 in 362, f in 288)
// grid: b*108 + ft*12 + at ; block 256 = (fsub 8) x (asub 32)
// ---------------------------------------------------------------------------
__global__ __launch_bounds__(256) void music_kernel(
    const float4* __restrict__ svr, const float4* __restrict__ svi,
    const double* __restrict__ rp, u16* __restrict__ muhi, u16* __restrict__ mulo)
{
    __shared__ double P[32][16];
    __shared__ float T[32][33];
    int bid = blockIdx.x;
    int at = bid % 12; bid /= 12;
    int ft = bid % 9;
    int b = bid / 9;
    int f0 = ft * 32, a0 = at * 32;
    int tid = threadIdx.x;
    for (int i = tid; i < 32 * 16; i += 256) {
        int fi = i >> 4, j = i & 15;
        int f = f0 + fi;
        P[fi][j] = (f < 257) ? rp[((size_t)b * 257 + f) * 16 + j] : 0.0;
    }
    __syncthreads();
    int asub = tid & 31, fsub = tid >> 5;
    int a = a0 + asub;
    #pragma unroll
    for (int k2 = 0; k2 < 4; ++k2) {
        int fl = fsub + 8 * k2;
        int f = f0 + fl;
        float val = 0.f;
        if (a < 360 && f < 257) {
            float4 u = svr[((size_t)b * 257 + f) * 360 + a];
            float4 w = svi[((size_t)b * 257 + f) * 360 + a];
            const double* Pf = P[fl];
            double ua[4] = {u.x, u.y, u.z, u.w};
            double wa[4] = {w.x, w.y, w.z, w.w};
            double qa = 0.0, qb = 0.0;
            #pragma unroll
            for (int m = 0; m < 4; ++m)
                #pragma unroll
                for (int n = 0; n < 4; ++n) {
                    double pmn = Pf[m * 4 + n];
                    qa += pmn * ua[m] * ua[n];
                    qb += pmn * wa[m] * wa[n];
                }
            double den = qa - qb;
            val = (float)(1.0 / fmax(den, 1e-6));
        }
        T[asub][fl] = val;
    }
    __syncthreads();
    #pragma unroll
    for (int p = 0; p < 4; ++p) {
        int row = p * 8 + (tid >> 5);
        int fc = tid & 31;
        int a2 = a0 + row;
        if (a2 < 360) {
            float v = T[row][fc];
            size_t o = (((size_t)b * 362) + a2 + 1) * 288 + f0 + fc;
            u16 hh = f2bf(v);
            muhi[o] = hh;
            mulo[o] = f2bf(v - bf2f(hh));
        }
    }
}

// ---------------------------------------------------------------------------
// attention: partial t-sums then finish (mean -> MLP -> sigmoid)
// sp2 layout: (b, t, f) f32, f-stride 257
// ---------------------------------------------------------------------------
__global__ __launch_bounds__(256) void attn_partial(const float* __restrict__ sp2, float* __restrict__ part)
{
    int bid = blockIdx.x;
    int ch = bid % 6;
    int b = bid / 6;
    int t0 = ch * 60;
    for (int f = threadIdx.x; f < 257; f += 256) {
        float s = 0.f;
        for (int t = 0; t < 60; ++t) s += sp2[((size_t)b * 360 + t0 + t) * 257 + f];
        part[((size_t)b * 6 + ch) * 257 + f] = s;
    }
}

__global__ __launch_bounds__(256) void attn_finish(
    const float* __restrict__ part, const float* __restrict__ w1,
    const float* __restrict__ w2, float* __restrict__ att)
{
    __shared__ float ys[257];
    __shared__ float hs[16];
    int b = blockIdx.x;
    int tid = threadIdx.x;
    for (int f = tid; f < 257; f += 256) {
        float s = 0.f;
        #pragma unroll
        for (int c = 0; c < 6; ++c) s += part[((size_t)b * 6 + c) * 257 + f];
        ys[f] = s * (1.0f / 360.0f);
    }
    __syncthreads();
    if (tid < 16) {
        float h = 0.f;
        for (int c = 0; c < 257; ++c) h = fmaf(ys[c], w1[(size_t)tid * 257 + c], h);
        hs[tid] = fmaxf(h, 0.f);
    }
    __syncthreads();
    for (int o = tid; o < 257; o += 256) {
        float a = 0.f;
        #pragma unroll
        for (int j = 0; j < 16; ++j) a = fmaf(hs[j], w2[(size_t)o * 16 + j], a);
        att[(size_t)b * 257 + o] = 1.0f / (1.0f + expf(-a));
    }
}

// ---------------------------------------------------------------------------
// conv1d 257->1 over att-weighted sp2(b,t,f), sigmoid -> outS (b,360)
// one warp per t
// ---------------------------------------------------------------------------
__global__ __launch_bounds__(256) void convs1_kernel(
    const float* __restrict__ sp2, const float* __restrict__ att,
    const float* __restrict__ w, const float* __restrict__ bb,
    float* __restrict__ outS)
{
    int bid = blockIdx.x;
    int tt = bid % 90;
    int b = bid / 90;
    int wv = threadIdx.x >> 6, l = threadIdx.x & 63;
    int t = tt * 4 + wv;
    float s = 0.f;
    for (int f = l; f < 257; f += 64) {
        float av = att[(size_t)b * 257 + f];
        float w0 = w[f * 3] * av, w1 = w[f * 3 + 1] * av, w2 = w[f * 3 + 2] * av;
        const float* col = sp2 + (size_t)b * 360 * 257 + f;
        if (t > 0)   s = fmaf(w0, col[(size_t)(t - 1) * 257], s);
        s = fmaf(w1, col[(size_t)t * 257], s);
        if (t < 359) s = fmaf(w2, col[(size_t)(t + 1) * 257], s);
    }
    #pragma unroll
    for (int off = 32; off > 0; off >>= 1) s += __shfl_down(s, off, 64);
    if (l == 0) outS[(size_t)b * 360 + t] = 1.0f / (1.0f + expf(-(s + bb[0])));
}

// ---------------------------------------------------------------------------
// top-5 soft-argmax (strict >: lowest index wins ties)
// ---------------------------------------------------------------------------
__global__ __launch_bounds__(64) void doa_kernel(const float* __restrict__ spec, float* __restrict__ doa)
{
    int b = threadIdx.x;
    const float* s = spec + (size_t)b * NANG;
    int idxs[5]; float vals[5];
    #pragma unroll
    for (int k = 0; k < 5; ++k) {
        float best = -3.4e38f; int bi = 0;
        for (int i = 0; i < NANG; ++i) {
            bool skip = false;
            #pragma unroll
            for (int j = 0; j < 5; ++j)
                if (j < k && idxs[j] == i) skip = true;
            float v = s[i];
            if (!skip && v > best) { best = v; bi = i; }
        }
        idxs[k] = bi; vals[k] = best;
    }
    float m = vals[0];
    float wsum = 0.f, asum = 0.f;
    #pragma unroll
    for (int k = 0; k < 5; ++k) {
        float wv = expf(20.0f * (vals[k] - m));
        wsum += wv;
        asum += wv * (float)idxs[k];
    }
    doa[b] = asum / wsum;
}

// ---------------------------------------------------------------------------
extern "C" void kernel_launch(void* const* d_in, const int* in_sizes, int n_in,
                              void* d_out, int out_size, void* d_ws, size_t ws_size,
                              hipStream_t stream)
{
    const float* X    = (const float*)d_in[0];
    const float* svr  = (const float*)d_in[1];
    const float* svi  = (const float*)d_in[2];
    const float* c1w  = (const float*)d_in[4];
    const float* c2w  = (const float*)d_in[5];
    const float* c3w  = (const float*)d_in[6];
    const float* c4w  = (const float*)d_in[7];
    const float* fcw  = (const float*)d_in[8];
    const float* fcb  = (const float*)d_in[9];
    const float* s2w  = (const float*)d_in[10];
    const float* s2b  = (const float*)d_in[11];
    const float* s1w  = (const float*)d_in[12];
    const float* s1b  = (const float*)d_in[13];
    const float* caw1 = (const float*)d_in[14];
    const float* caw2 = (const float*)d_in[15];
    const float* bn1g = (const float*)d_in[16]; const float* bn1b = (const float*)d_in[17];
    const float* bn1m = (const float*)d_in[18]; const float* bn1v = (const float*)d_in[19];
    const float* bn2g = (const float*)d_in[20]; const float* bn2b = (const float*)d_in[21];
    const float* bn2m = (const float*)d_in[22]; const float* bn2v = (const float*)d_in[23];
    const float* bn3g = (const float*)d_in[24]; const float* bn3b = (const float*)d_in[25];
    const float* bn3m = (const float*)d_in[26]; const float* bn3v = (const float*)d_in[27];
    const float* bn4g = (const float*)d_in[28]; const float* bn4b = (const float*)d_in[29];
    const float* bn4m = (const float*)d_in[30]; const float* bn4v = (const float*)d_in[31];

    char* wsb = (char*)d_ws;
    // region A (time-disjoint: xp -> c3 -> mu)
    u16* xp_hi = (u16*)(wsb + 0);
    u16* xp_lo = (u16*)(wsb + 17305600);
    u16* c3_hi = (u16*)(wsb + 0);
    u16* c3_lo = (u16*)(wsb + 9469952);
    u16* mu_hi = (u16*)(wsb + 0);
    u16* mu_lo = (u16*)(wsb + 13344768);
    // region B (c2 -> {z, zfc, rp, sp2, part, att})
    const size_t Bb = 34611200;
    u16*   c2_hi = (u16*)(wsb + Bb);
    u16*   c2_lo = (u16*)(wsb + Bb + 35684352);
    float*  zbuf = (float*)(wsb + Bb);
    float*  zfc  = (float*)(wsb + Bb + 4210688);
    double* rp   = (double*)(wsb + Bb + 6316032);
    float*  sp2  = (float*)(wsb + Bb + 8421376);
    float*  part = (float*)(wsb + Bb + 32106496);
    float*  att  = (float*)(wsb + Bb + 32501248);
    // region C (persistent small)
    const size_t Cb = Bb + 71368704;
    u16* c4_hi = (u16*)(wsb + Cb);
    u16* c4_lo = (u16*)(wsb + Cb + 2654208);
    u16* bp1 = (u16*)(wsb + Cb + 5308416);
    u16* bp2 = (u16*)(wsb + Cb + 5382144);
    u16* bp3 = (u16*)(wsb + Cb + 5529600);
    u16* bp4 = (u16*)(wsb + Cb + 5677056);
    u16* bp5 = (u16*)(wsb + Cb + 6414336);
    float* bns = (float*)(wsb + Cb + 7409664);

    float* outD = (float*)d_out;
    float* outS = (float*)d_out + 64;

    // --- prep ---
    bnprep<<<4, 256, 0, stream>>>(bn1g, bn1b, bn1m, bn1v, bn2g, bn2b, bn2m, bn2v,
                                  bn3g, bn3b, bn3m, bn3v, bn4g, bn4b, bn4m, bn4v, bns);
    bpack<<<18, 256, 0, stream>>>(c1w, bp1, 8, 64, 9, 1, 4);
    bpack<<<36, 256, 0, stream>>>(c2w, bp2, 64, 64, 9, 2, 4);
    bpack<<<36, 256, 0, stream>>>(c3w, bp3, 64, 64, 9, 2, 4);
    bpack<<<180, 256, 0, stream>>>(c4w, bp4, 64, 257, 9, 2, 20);
    bpack<<<243, 256, 0, stream>>>(s2w, bp5, 257, 257, 3, 9, 18);
    xpack_kernel<<<64 * 130, 256, 0, stream>>>(X, xp_hi, xp_lo);
    zpad<<<4161, 256, 0, stream>>>(c2_hi, c2_lo, 64, 66, 66, 64, 1);
    zpad<<<1088, 256, 0, stream>>>(c4_hi, c4_lo, 64, 18, 18, 64, 1);

    // --- conv1: 8ch 128x128 -> c2 (66x66x64 padded) ---
    conv_gemm<8, 128, 128, 64, 2, 3, 3, 4, 4, 48, 0, true, 4>
        <<<dim3(64 * 64, 1), 256, 0, stream>>>(xp_hi, xp_lo, bp1, bns, bns + 512, c2_hi, c2_lo, nullptr);
    zpad<<<2112, 256, 0, stream>>>(c3_hi, c3_lo, 64, 34, 34, 64, 1);  // A region free now
    // --- conv2 ---
    conv_gemm<64, 64, 64, 64, 2, 3, 3, 4, 2, 144, 0, false, 4>
        <<<dim3(64 * 32, 1), 256, 0, stream>>>(c2_hi, c2_lo, bp2, bns + 1024, bns + 1536, c3_hi, c3_lo, nullptr);
    // --- conv3 ---
    conv_gemm<64, 32, 32, 64, 4, 3, 3, 4, 2, 144, 0, false, 4>
        <<<dim3(64 * 8, 1), 256, 0, stream>>>(c3_hi, c3_lo, bp3, bns + 2048, bns + 2560, c4_hi, c4_lo, nullptr);
    zpad<<<144, 256, 0, stream>>>(mu_hi, mu_lo, 64, 362, 1, 288, 0);  // A region free now
    // --- conv4 -> z f32 (b,8,8,257) ---
    conv_gemm<64, 16, 16, 257, 8, 3, 3, 4, 2, 144, 1, false, 20>
        <<<dim3(64 * 2, 5), 256, 0, stream>>>(c4_hi, c4_lo, bp4, bns + 3072, bns + 3584, nullptr, nullptr, zbuf);

    fc_kernel<<<64 * 33, 256, 0, stream>>>(zbuf, fcw, fcb, zfc);
    eigh_kernel<<<NFB, 64, 0, stream>>>(zfc, rp);
    music_kernel<<<64 * 108, 256, 0, stream>>>((const float4*)svr, (const float4*)svi, rp, mu_hi, mu_lo);
    // --- convs2 (1D conv as shift-GEMM: KH=3,KW=1,W=1,H=360) -> sp2 (b,t,f) ---
    conv_gemm<288, 360, 1, 257, 64, 3, 1, 9, 1, 592, 2, false, 18>
        <<<dim3(64 * 6, 2), 256, 0, stream>>>(mu_hi, mu_lo, bp5, nullptr, s2b, nullptr, nullptr, sp2);

    attn_partial<<<64 * 6, 256, 0, stream>>>(sp2, part);
    attn_finish<<<64, 256, 0, stream>>>(part, caw1, caw2, att);
    convs1_kernel<<<64 * 90, 256, 0, stream>>>(sp2, att, s1w, s1b, outS);
    doa_kernel<<<1, 64, 0, stream>>>(outS, outD);
}